// Round 5
// baseline (168705.054 us; speedup 1.0000x reference)
//
#include <hip/hip_runtime.h>
#include <cstdint>
#include <cstddef>

#define UU 1024
#define FOURU 4096
#define BATCH 64
#define TTT 128
#define SSS 16
#define BU 65536  // BATCH*UU elems per time plane
#define NBLK 256
#define NW 8      // waves per block

typedef __attribute__((ext_vector_type(8))) short short8;
typedef __attribute__((ext_vector_type(4))) float f32x4;

__device__ __forceinline__ unsigned short f2bf(float f) {
    union { float f; uint32_t u; } v; v.f = f;
    uint32_t u = v.u;
    uint32_t r = (u + 0x7fffu + ((u >> 16) & 1u)) >> 16;
    return (unsigned short)r;
}
__device__ __forceinline__ float bf2f(unsigned short h) {
    union { uint32_t u; float f; } v; v.u = ((uint32_t)h) << 16;
    return v.f;
}

// ---------------------------------------------------------------------------
// Manual grid barrier (sense-reversing). bar[0]=arrival, bar[16]=generation.
// ---------------------------------------------------------------------------
__device__ __forceinline__ void grid_barrier(unsigned int* bar) {
    __syncthreads();
    if (threadIdx.x == 0) {
        unsigned int g = __hip_atomic_load(bar + 16, __ATOMIC_RELAXED, __HIP_MEMORY_SCOPE_AGENT);
        unsigned int a = __hip_atomic_fetch_add(bar, 1u, __ATOMIC_ACQ_REL, __HIP_MEMORY_SCOPE_AGENT);
        if (a == NBLK - 1u) {
            __hip_atomic_store(bar, 0u, __ATOMIC_RELAXED, __HIP_MEMORY_SCOPE_AGENT);
            __hip_atomic_store(bar + 16, g + 1u, __ATOMIC_RELEASE, __HIP_MEMORY_SCOPE_AGENT);
        } else {
            while (__hip_atomic_load(bar + 16, __ATOMIC_ACQUIRE, __HIP_MEMORY_SCOPE_AGENT) == g) {
                __builtin_amdgcn_s_sleep(1);
            }
        }
    }
    __syncthreads();
}

__global__ void bar_init(unsigned int* bar) {
    bar[threadIdx.x] = 0u;  // 64 words
}

// ---------------------------------------------------------------------------
// Repack weights: W[k][origcol] f32 -> packed [pc][K] bf16 hi/lo;
// pc = blk*16 + g*4 + j <-> origcol = g*1024 + blk*4 + j.
// ---------------------------------------------------------------------------
__global__ void repack_w1(const float* __restrict__ r1,
                          unsigned short* __restrict__ whi,
                          unsigned short* __restrict__ wlo) {
    int idx = blockIdx.x * 256 + threadIdx.x;
    int pc = idx >> 10, k = idx & 1023;
    int b = pc >> 4, g = (pc >> 2) & 3, j = pc & 3;
    int oc = g * UU + b * 4 + j;
    float v = r1[(size_t)k * FOURU + oc];
    unsigned short hi = f2bf(v);
    whi[idx] = hi;
    wlo[idx] = f2bf(v - bf2f(hi));
}

__global__ void repack_w2(const float* __restrict__ k2, const float* __restrict__ r2,
                          unsigned short* __restrict__ whi,
                          unsigned short* __restrict__ wlo) {
    int idx = blockIdx.x * 256 + threadIdx.x;
    int pc = idx >> 11, k = idx & 2047;
    int b = pc >> 4, g = (pc >> 2) & 3, j = pc & 3;
    int oc = g * UU + b * 4 + j;
    float v = (k < UU) ? k2[(size_t)k * FOURU + oc]
                       : r2[(size_t)(k - UU) * FOURU + oc];
    unsigned short hi = f2bf(v);
    whi[idx] = hi;
    wlo[idx] = f2bf(v - bf2f(hi));
}

// ---------------------------------------------------------------------------
// Persistent kernel: 256 blocks x 512 threads (8 waves), 1 block/CU.
// Block blk owns packed cols blk*16..+15 for BOTH layers. 8 waves split K
// (layer1: 128 k/wave; layer2: 256 k/wave). Weights pinned in VGPRs via
// opaque asm (defeats rematerialization). h via global bf16 hi/lo planes;
// c in per-thread registers.
// ---------------------------------------------------------------------------
__global__ __launch_bounds__(512, 1) void feedback_persistent(
    const unsigned short* __restrict__ W1hi, const unsigned short* __restrict__ W1lo,
    const unsigned short* __restrict__ W2hi, const unsigned short* __restrict__ W2lo,
    unsigned short* __restrict__ X1hi, unsigned short* __restrict__ X1lo,
    unsigned short* __restrict__ X2hi, unsigned short* __restrict__ X2lo,
    const float* __restrict__ inputs, const float* __restrict__ k1,
    const float* __restrict__ b1, const float* __restrict__ b2,
    const float* __restrict__ wd, const float* __restrict__ bd,
    float* __restrict__ out, unsigned int* bar) {
    __shared__ float zp[NW][64][16];

    const int tid = threadIdx.x;
    const int lane = tid & 63;
    const int w = tid >> 6;          // 0..7
    const int blk = blockIdx.x;
    const int kg8 = (lane >> 4) * 8;
    const int colpc = blk * 16 + (lane & 15);

    // ---- weights -> VGPRs (once); opaque-pin so they cannot be remat'd ----
    short8 w1h[4], w1l[4], w2h[8], w2l[8];
    {
        const size_t base1 = (size_t)colpc * 1024 + (size_t)w * 128 + kg8;
#pragma unroll
        for (int i = 0; i < 4; ++i) {
            w1h[i] = *(const short8*)(W1hi + base1 + i * 32);
            w1l[i] = *(const short8*)(W1lo + base1 + i * 32);
            asm volatile("" : "+v"(w1h[i]), "+v"(w1l[i]));
        }
        const size_t base2 = (size_t)colpc * 2048 + (size_t)w * 256 + kg8;
#pragma unroll
        for (int i = 0; i < 8; ++i) {
            w2h[i] = *(const short8*)(W2hi + base2 + i * 32);
            w2l[i] = *(const short8*)(W2lo + base2 + i * 32);
            asm volatile("" : "+v"(w2h[i]), "+v"(w2l[i]));
        }
    }

    // ---- epilogue mapping: first 256 threads, (row, unit) ----
    const int erow = (tid & 255) >> 2;   // 0..63
    const int ej = tid & 3;              // 0..3
    const int eu = blk * 4 + ej;
    float b1v[4], b2v[4], k1v[4];
#pragma unroll
    for (int g = 0; g < 4; ++g) {
        const int oc = g * UU + blk * 4 + ej;
        b1v[g] = b1[oc];
        b2v[g] = b2[oc];
        k1v[g] = k1[oc];
    }
    float c1 = 0.f, c2 = 0.f;

    const int gw = blk * NW + w;  // 0..2047 global wave id

    for (int s = 0; s < SSS; ++s) {
        // ================= LSTM1 scan (K=1024, 128/wave) ===================
        for (int t = 0; t < TTT; ++t) {
            f32x4 acc[4] = {};
            if (!(s == 0 && t == 0)) {
                const unsigned short *Ah, *Al;
                if (t == 0) { Ah = X2hi + 127 * BU; Al = X2lo + 127 * BU; }
                else        { Ah = X1hi + (size_t)(t - 1) * BU; Al = X1lo + (size_t)(t - 1) * BU; }
                const int koff = w * 128;
#pragma unroll
                for (int i = 0; i < 4; ++i) {
                    const int kk = i * 32;
#pragma unroll
                    for (int m = 0; m < 4; ++m) {
                        const int row = m * 16 + (lane & 15);
                        const size_t aoff = (size_t)row * UU + koff + kk + kg8;
                        short8 ah = *(const short8*)(Ah + aoff);
                        short8 al = *(const short8*)(Al + aoff);
                        acc[m] = __builtin_amdgcn_mfma_f32_16x16x32_bf16(ah, w1h[i], acc[m], 0, 0, 0);
                        acc[m] = __builtin_amdgcn_mfma_f32_16x16x32_bf16(al, w1h[i], acc[m], 0, 0, 0);
                        acc[m] = __builtin_amdgcn_mfma_f32_16x16x32_bf16(ah, w1l[i], acc[m], 0, 0, 0);
                    }
                }
            }
#pragma unroll
            for (int m = 0; m < 4; ++m) {
                const int rbase = m * 16 + (lane >> 4) * 4;
#pragma unroll
                for (int r = 0; r < 4; ++r)
                    zp[w][rbase + r][lane & 15] = acc[m][r];
            }
            __syncthreads();
            if (tid < 256) {
                float xv = (s == 0) ? inputs[(size_t)erow * TTT + t]
                                    : out[(size_t)erow * (SSS * TTT) + (s - 1) * TTT + t];
                float z[4];
#pragma unroll
                for (int g = 0; g < 4; ++g) {
                    float sum = 0.f;
#pragma unroll
                    for (int ww = 0; ww < NW; ++ww) sum += zp[ww][erow][g * 4 + ej];
                    z[g] = sum + b1v[g] + xv * k1v[g];
                }
                float cold = (t == 0) ? c2 : c1;  // c2: 0 at s==0; lstm2 final c of s-1 else
                float ig = 1.f / (1.f + expf(-z[0]));
                float fg = 1.f / (1.f + expf(-z[1]));
                float gg = tanhf(z[2]);
                float og = 1.f / (1.f + expf(-z[3]));
                float cn = fg * cold + ig * gg;
                float hn = og * tanhf(cn);
                c1 = cn;
                unsigned short hh = f2bf(hn);
                const size_t hoff = (size_t)t * BU + (size_t)erow * UU + eu;
                X1hi[hoff] = hh;
                X1lo[hoff] = f2bf(hn - bf2f(hh));
            }
            grid_barrier(bar);
        }
        // ================= LSTM2 scan (K=2048, 256/wave) ===================
        for (int t = 0; t < TTT; ++t) {
            f32x4 acc[4] = {};
            const bool skiph = (s == 0 && t == 0);  // warmup: h2_0 = 0
            {
                const unsigned short *Ah, *Al;
                int koff;
                if (w < 4) {  // x half, k in [0,1024)
                    Ah = X1hi + (size_t)t * BU;
                    Al = X1lo + (size_t)t * BU;
                    koff = w * 256;
                } else {      // h half, k in [1024,2048)
                    if (t == 0) { Ah = X1hi + 127 * BU; Al = X1lo + 127 * BU; }  // h2_init = h1_final
                    else        { Ah = X2hi + (size_t)(t - 1) * BU; Al = X2lo + (size_t)(t - 1) * BU; }
                    koff = (w - 4) * 256;
                }
                if (!(skiph && w >= 4)) {
#pragma unroll
                    for (int i = 0; i < 8; ++i) {
                        const int kk = i * 32;
#pragma unroll
                        for (int m = 0; m < 4; ++m) {
                            const int row = m * 16 + (lane & 15);
                            const size_t aoff = (size_t)row * UU + koff + kk + kg8;
                            short8 ah = *(const short8*)(Ah + aoff);
                            short8 al = *(const short8*)(Al + aoff);
                            acc[m] = __builtin_amdgcn_mfma_f32_16x16x32_bf16(ah, w2h[i], acc[m], 0, 0, 0);
                            acc[m] = __builtin_amdgcn_mfma_f32_16x16x32_bf16(al, w2h[i], acc[m], 0, 0, 0);
                            acc[m] = __builtin_amdgcn_mfma_f32_16x16x32_bf16(ah, w2l[i], acc[m], 0, 0, 0);
                        }
                    }
                }
            }
#pragma unroll
            for (int m = 0; m < 4; ++m) {
                const int rbase = m * 16 + (lane >> 4) * 4;
#pragma unroll
                for (int r = 0; r < 4; ++r)
                    zp[w][rbase + r][lane & 15] = acc[m][r];
            }
            __syncthreads();
            if (tid < 256) {
                float z[4];
#pragma unroll
                for (int g = 0; g < 4; ++g) {
                    float sum = 0.f;
#pragma unroll
                    for (int ww = 0; ww < NW; ++ww) sum += zp[ww][erow][g * 4 + ej];
                    z[g] = sum + b2v[g];
                }
                float cold = (t == 0) ? ((s == 0) ? 0.f : c1) : c2;
                float ig = 1.f / (1.f + expf(-z[0]));
                float fg = 1.f / (1.f + expf(-z[1]));
                float gg = tanhf(z[2]);
                float og = 1.f / (1.f + expf(-z[3]));
                float cn = fg * cold + ig * gg;
                float hn = og * tanhf(cn);
                c2 = cn;
                unsigned short hh = f2bf(hn);
                const size_t hoff = (size_t)t * BU + (size_t)erow * UU + eu;
                X2hi[hoff] = hh;
                X2lo[hoff] = f2bf(hn - bf2f(hh));
            }
            grid_barrier(bar);
        }
        // ================= dense head over full sequence ====================
        // 2048 waves x 4 dots = 8192 (t,b) dot products of length 1024
#pragma unroll
        for (int i = 0; i < 4; ++i) {
            const int d = gw + 2048 * i;
            const int t = d >> 6, b = d & 63;
            const unsigned short* ph = X2hi + (size_t)t * BU + (size_t)b * UU;
            const unsigned short* pl = X2lo + (size_t)t * BU + (size_t)b * UU;
            float ssum = 0.f;
#pragma unroll 4
            for (int ii = lane; ii < UU; ii += 64)
                ssum += (bf2f(ph[ii]) + bf2f(pl[ii])) * wd[ii];
#pragma unroll
            for (int off = 32; off; off >>= 1) ssum += __shfl_down(ssum, off, 64);
            if (lane == 0) out[(size_t)b * (SSS * TTT) + s * TTT + t] = ssum + bd[0];
        }
        grid_barrier(bar);
    }
}

// ---------------------------------------------------------------------------
extern "C" void kernel_launch(void* const* d_in, const int* in_sizes, int n_in,
                              void* d_out, int out_size, void* d_ws, size_t ws_size,
                              hipStream_t stream) {
    const float* inputs = (const float*)d_in[0];  // [64,128,1]
    const float* k1     = (const float*)d_in[1];  // [1,4096]
    const float* r1     = (const float*)d_in[2];  // [1024,4096]
    const float* b1     = (const float*)d_in[3];  // [4096]
    const float* k2     = (const float*)d_in[4];  // [1024,4096]
    const float* r2     = (const float*)d_in[5];  // [1024,4096]
    const float* b2     = (const float*)d_in[6];  // [4096]
    const float* wd     = (const float*)d_in[7];  // [1024,1]
    const float* bd     = (const float*)d_in[8];  // [1]
    float* out = (float*)d_out;                   // [64, 16*128, 1]

    char* ws = (char*)d_ws;
    size_t off = 0;
    auto carve = [&](size_t bytes) -> void* {
        void* p = ws + off;
        off += (bytes + 255) & ~(size_t)255;
        return p;
    };
    unsigned short* W1hi = (unsigned short*)carve((size_t)FOURU * UU * 2);
    unsigned short* W1lo = (unsigned short*)carve((size_t)FOURU * UU * 2);
    unsigned short* W2hi = (unsigned short*)carve((size_t)FOURU * 2048 * 2);
    unsigned short* W2lo = (unsigned short*)carve((size_t)FOURU * 2048 * 2);
    unsigned short* X1hi = (unsigned short*)carve((size_t)TTT * BU * 2);
    unsigned short* X1lo = (unsigned short*)carve((size_t)TTT * BU * 2);
    unsigned short* X2hi = (unsigned short*)carve((size_t)TTT * BU * 2);
    unsigned short* X2lo = (unsigned short*)carve((size_t)TTT * BU * 2);
    unsigned int* bar = (unsigned int*)carve(256);

    bar_init<<<dim3(1), dim3(64), 0, stream>>>(bar);
    repack_w1<<<dim3((FOURU * UU) / 256), dim3(256), 0, stream>>>(r1, W1hi, W1lo);
    repack_w2<<<dim3((FOURU * 2048) / 256), dim3(256), 0, stream>>>(k2, r2, W2hi, W2lo);

    feedback_persistent<<<dim3(NBLK), dim3(512), 0, stream>>>(
        W1hi, W1lo, W2hi, W2lo, X1hi, X1lo, X2hi, X2lo,
        inputs, k1, b1, b2, wd, bd, out, bar);
}

// Round 6
// 120146.277 us; speedup vs baseline: 1.4042x; 1.4042x over previous
//
#include <hip/hip_runtime.h>
#include <cstdint>
#include <cstddef>

#define UU 1024
#define FOURU 4096
#define BATCH 64
#define TTT 128
#define SSS 16
#define BU 65536  // BATCH*UU elems per time plane
#define NBLK 256
#define NW 8      // waves per block

typedef __attribute__((ext_vector_type(8))) short short8;
typedef __attribute__((ext_vector_type(4))) float f32x4;

__device__ __forceinline__ unsigned short f2bf(float f) {
    union { float f; uint32_t u; } v; v.f = f;
    uint32_t u = v.u;
    uint32_t r = (u + 0x7fffu + ((u >> 16) & 1u)) >> 16;
    return (unsigned short)r;
}
__device__ __forceinline__ float bf2f(unsigned short h) {
    union { uint32_t u; float f; } v; v.u = ((uint32_t)h) << 16;
    return v.f;
}

// ---------------------------------------------------------------------------
// Manual grid barrier. bar[0]=arrival, bar[16]=generation.
// Arrival: RELEASE fetch_add (buffer_wbl2 publishes this block's h stores).
// Spin: RELAXED agent loads — read-through (coherent), NO buffer_inv per poll.
// Exit: ONE ACQUIRE load (single L2 invalidate per block per step).
// ---------------------------------------------------------------------------
__device__ __forceinline__ void grid_barrier(unsigned int* bar) {
    __syncthreads();
    if (threadIdx.x == 0) {
        unsigned int g = __hip_atomic_load(bar + 16, __ATOMIC_RELAXED, __HIP_MEMORY_SCOPE_AGENT);
        unsigned int a = __hip_atomic_fetch_add(bar, 1u, __ATOMIC_RELEASE, __HIP_MEMORY_SCOPE_AGENT);
        if (a == NBLK - 1u) {
            __hip_atomic_store(bar, 0u, __ATOMIC_RELAXED, __HIP_MEMORY_SCOPE_AGENT);
            __hip_atomic_store(bar + 16, g + 1u, __ATOMIC_RELEASE, __HIP_MEMORY_SCOPE_AGENT);
        } else {
            while (__hip_atomic_load(bar + 16, __ATOMIC_RELAXED, __HIP_MEMORY_SCOPE_AGENT) == g) {
                __builtin_amdgcn_s_sleep(1);
            }
        }
        (void)__hip_atomic_load(bar + 16, __ATOMIC_ACQUIRE, __HIP_MEMORY_SCOPE_AGENT);
    }
    __syncthreads();
}

__global__ void bar_init(unsigned int* bar) {
    bar[threadIdx.x] = 0u;  // 64 words
}

// ---------------------------------------------------------------------------
// Repack weights: W[k][origcol] f32 -> packed [pc][K] bf16 hi/lo;
// pc = blk*16 + g*4 + j <-> origcol = g*1024 + blk*4 + j.
// ---------------------------------------------------------------------------
__global__ void repack_w1(const float* __restrict__ r1,
                          unsigned short* __restrict__ whi,
                          unsigned short* __restrict__ wlo) {
    int idx = blockIdx.x * 256 + threadIdx.x;
    int pc = idx >> 10, k = idx & 1023;
    int b = pc >> 4, g = (pc >> 2) & 3, j = pc & 3;
    int oc = g * UU + b * 4 + j;
    float v = r1[(size_t)k * FOURU + oc];
    unsigned short hi = f2bf(v);
    whi[idx] = hi;
    wlo[idx] = f2bf(v - bf2f(hi));
}

__global__ void repack_w2(const float* __restrict__ k2, const float* __restrict__ r2,
                          unsigned short* __restrict__ whi,
                          unsigned short* __restrict__ wlo) {
    int idx = blockIdx.x * 256 + threadIdx.x;
    int pc = idx >> 11, k = idx & 2047;
    int b = pc >> 4, g = (pc >> 2) & 3, j = pc & 3;
    int oc = g * UU + b * 4 + j;
    float v = (k < UU) ? k2[(size_t)k * FOURU + oc]
                       : r2[(size_t)(k - UU) * FOURU + oc];
    unsigned short hi = f2bf(v);
    whi[idx] = hi;
    wlo[idx] = f2bf(v - bf2f(hi));
}

// ---------------------------------------------------------------------------
// Persistent kernel: 256 blocks x 512 threads (8 waves), 1 block/CU.
// Block blk owns packed cols blk*16..+15 for BOTH layers. 8 waves split K.
// Weights pinned in VGPRs (opaque asm). h via global bf16 hi/lo planes;
// c in per-thread registers. One grid barrier per cell step.
// ---------------------------------------------------------------------------
__global__ __launch_bounds__(512, 1) void feedback_persistent(
    const unsigned short* __restrict__ W1hi, const unsigned short* __restrict__ W1lo,
    const unsigned short* __restrict__ W2hi, const unsigned short* __restrict__ W2lo,
    unsigned short* __restrict__ X1hi, unsigned short* __restrict__ X1lo,
    unsigned short* __restrict__ X2hi, unsigned short* __restrict__ X2lo,
    const float* __restrict__ inputs, const float* __restrict__ k1,
    const float* __restrict__ b1, const float* __restrict__ b2,
    const float* __restrict__ wd, const float* __restrict__ bd,
    float* __restrict__ out, unsigned int* bar) {
    __shared__ float zp[NW][64][17];   // +1 pad: stride 17 coprime with 32 banks

    const int tid = threadIdx.x;
    const int lane = tid & 63;
    const int w = tid >> 6;          // 0..7
    const int blk = blockIdx.x;
    const int kg8 = (lane >> 4) * 8;
    const int colpc = blk * 16 + (lane & 15);

    // ---- weights -> VGPRs (once); opaque-pin so they cannot be remat'd ----
    short8 w1h[4], w1l[4], w2h[8], w2l[8];
    {
        const size_t base1 = (size_t)colpc * 1024 + (size_t)w * 128 + kg8;
#pragma unroll
        for (int i = 0; i < 4; ++i) {
            w1h[i] = *(const short8*)(W1hi + base1 + i * 32);
            w1l[i] = *(const short8*)(W1lo + base1 + i * 32);
            asm volatile("" : "+v"(w1h[i]), "+v"(w1l[i]));
        }
        const size_t base2 = (size_t)colpc * 2048 + (size_t)w * 256 + kg8;
#pragma unroll
        for (int i = 0; i < 8; ++i) {
            w2h[i] = *(const short8*)(W2hi + base2 + i * 32);
            w2l[i] = *(const short8*)(W2lo + base2 + i * 32);
            asm volatile("" : "+v"(w2h[i]), "+v"(w2l[i]));
        }
    }

    // ---- epilogue mapping: first 256 threads, (row, unit) ----
    const int erow = (tid & 255) >> 2;   // 0..63
    const int ej = tid & 3;              // 0..3
    const int eu = blk * 4 + ej;
    float b1v[4], b2v[4], k1v[4];
#pragma unroll
    for (int g = 0; g < 4; ++g) {
        const int oc = g * UU + blk * 4 + ej;
        b1v[g] = b1[oc];
        b2v[g] = b2[oc];
        k1v[g] = k1[oc];
    }
    float c1 = 0.f, c2 = 0.f;

    const int gw = blk * NW + w;  // 0..2047 global wave id

    for (int s = 0; s < SSS; ++s) {
        // ================= LSTM1 scan (K=1024, 128/wave) ===================
        for (int t = 0; t < TTT; ++t) {
            f32x4 acc[4] = {};
            if (!(s == 0 && t == 0)) {
                const unsigned short *Ah, *Al;
                if (t == 0) { Ah = X2hi + 127 * BU; Al = X2lo + 127 * BU; }
                else        { Ah = X1hi + (size_t)(t - 1) * BU; Al = X1lo + (size_t)(t - 1) * BU; }
                const int koff = w * 128;
#pragma unroll
                for (int i = 0; i < 4; ++i) {
                    const int kk = i * 32;
#pragma unroll
                    for (int m = 0; m < 4; ++m) {
                        const int row = m * 16 + (lane & 15);
                        const size_t aoff = (size_t)row * UU + koff + kk + kg8;
                        short8 ah = *(const short8*)(Ah + aoff);
                        short8 al = *(const short8*)(Al + aoff);
                        acc[m] = __builtin_amdgcn_mfma_f32_16x16x32_bf16(ah, w1h[i], acc[m], 0, 0, 0);
                        acc[m] = __builtin_amdgcn_mfma_f32_16x16x32_bf16(al, w1h[i], acc[m], 0, 0, 0);
                        acc[m] = __builtin_amdgcn_mfma_f32_16x16x32_bf16(ah, w1l[i], acc[m], 0, 0, 0);
                    }
                }
            }
#pragma unroll
            for (int m = 0; m < 4; ++m) {
                const int rbase = m * 16 + (lane >> 4) * 4;
#pragma unroll
                for (int r = 0; r < 4; ++r)
                    zp[w][rbase + r][lane & 15] = acc[m][r];
            }
            __syncthreads();
            if (tid < 256) {
                float xv = (s == 0) ? inputs[(size_t)erow * TTT + t]
                                    : out[(size_t)erow * (SSS * TTT) + (s - 1) * TTT + t];
                float z[4];
#pragma unroll
                for (int g = 0; g < 4; ++g) {
                    float sum = 0.f;
#pragma unroll
                    for (int ww = 0; ww < NW; ++ww) sum += zp[ww][erow][g * 4 + ej];
                    z[g] = sum + b1v[g] + xv * k1v[g];
                }
                float cold = (t == 0) ? c2 : c1;  // c2: 0 at s==0; lstm2 final c of s-1 else
                float ig = 1.f / (1.f + expf(-z[0]));
                float fg = 1.f / (1.f + expf(-z[1]));
                float gg = tanhf(z[2]);
                float og = 1.f / (1.f + expf(-z[3]));
                float cn = fg * cold + ig * gg;
                float hn = og * tanhf(cn);
                c1 = cn;
                unsigned short hh = f2bf(hn);
                const size_t hoff = (size_t)t * BU + (size_t)erow * UU + eu;
                X1hi[hoff] = hh;
                X1lo[hoff] = f2bf(hn - bf2f(hh));
            }
            grid_barrier(bar);
        }
        // ================= LSTM2 scan (K=2048, 256/wave) ===================
        for (int t = 0; t < TTT; ++t) {
            f32x4 acc[4] = {};
            const bool skiph = (s == 0 && t == 0);  // warmup: h2_0 = 0
            {
                const unsigned short *Ah, *Al;
                int koff;
                if (w < 4) {  // x half, k in [0,1024)
                    Ah = X1hi + (size_t)t * BU;
                    Al = X1lo + (size_t)t * BU;
                    koff = w * 256;
                } else {      // h half, k in [1024,2048)
                    if (t == 0) { Ah = X1hi + 127 * BU; Al = X1lo + 127 * BU; }  // h2_init = h1_final
                    else        { Ah = X2hi + (size_t)(t - 1) * BU; Al = X2lo + (size_t)(t - 1) * BU; }
                    koff = (w - 4) * 256;
                }
                if (!(skiph && w >= 4)) {
#pragma unroll
                    for (int i = 0; i < 8; ++i) {
                        const int kk = i * 32;
#pragma unroll
                        for (int m = 0; m < 4; ++m) {
                            const int row = m * 16 + (lane & 15);
                            const size_t aoff = (size_t)row * UU + koff + kk + kg8;
                            short8 ah = *(const short8*)(Ah + aoff);
                            short8 al = *(const short8*)(Al + aoff);
                            acc[m] = __builtin_amdgcn_mfma_f32_16x16x32_bf16(ah, w2h[i], acc[m], 0, 0, 0);
                            acc[m] = __builtin_amdgcn_mfma_f32_16x16x32_bf16(al, w2h[i], acc[m], 0, 0, 0);
                            acc[m] = __builtin_amdgcn_mfma_f32_16x16x32_bf16(ah, w2l[i], acc[m], 0, 0, 0);
                        }
                    }
                }
            }
#pragma unroll
            for (int m = 0; m < 4; ++m) {
                const int rbase = m * 16 + (lane >> 4) * 4;
#pragma unroll
                for (int r = 0; r < 4; ++r)
                    zp[w][rbase + r][lane & 15] = acc[m][r];
            }
            __syncthreads();
            if (tid < 256) {
                float z[4];
#pragma unroll
                for (int g = 0; g < 4; ++g) {
                    float sum = 0.f;
#pragma unroll
                    for (int ww = 0; ww < NW; ++ww) sum += zp[ww][erow][g * 4 + ej];
                    z[g] = sum + b2v[g];
                }
                float cold = (t == 0) ? ((s == 0) ? 0.f : c1) : c2;
                float ig = 1.f / (1.f + expf(-z[0]));
                float fg = 1.f / (1.f + expf(-z[1]));
                float gg = tanhf(z[2]);
                float og = 1.f / (1.f + expf(-z[3]));
                float cn = fg * cold + ig * gg;
                float hn = og * tanhf(cn);
                c2 = cn;
                unsigned short hh = f2bf(hn);
                const size_t hoff = (size_t)t * BU + (size_t)erow * UU + eu;
                X2hi[hoff] = hh;
                X2lo[hoff] = f2bf(hn - bf2f(hh));
            }
            grid_barrier(bar);
        }
        // ================= dense head over full sequence ====================
        // 2048 waves x 4 dots = 8192 (t,b) dot products of length 1024
#pragma unroll
        for (int i = 0; i < 4; ++i) {
            const int d = gw + 2048 * i;
            const int t = d >> 6, b = d & 63;
            const unsigned short* ph = X2hi + (size_t)t * BU + (size_t)b * UU;
            const unsigned short* pl = X2lo + (size_t)t * BU + (size_t)b * UU;
            float ssum = 0.f;
#pragma unroll 4
            for (int ii = lane; ii < UU; ii += 64)
                ssum += (bf2f(ph[ii]) + bf2f(pl[ii])) * wd[ii];
#pragma unroll
            for (int off = 32; off; off >>= 1) ssum += __shfl_down(ssum, off, 64);
            if (lane == 0) out[(size_t)b * (SSS * TTT) + s * TTT + t] = ssum + bd[0];
        }
        grid_barrier(bar);
    }
}

// ---------------------------------------------------------------------------
extern "C" void kernel_launch(void* const* d_in, const int* in_sizes, int n_in,
                              void* d_out, int out_size, void* d_ws, size_t ws_size,
                              hipStream_t stream) {
    const float* inputs = (const float*)d_in[0];  // [64,128,1]
    const float* k1     = (const float*)d_in[1];  // [1,4096]
    const float* r1     = (const float*)d_in[2];  // [1024,4096]
    const float* b1     = (const float*)d_in[3];  // [4096]
    const float* k2     = (const float*)d_in[4];  // [1024,4096]
    const float* r2     = (const float*)d_in[5];  // [1024,4096]
    const float* b2     = (const float*)d_in[6];  // [4096]
    const float* wd     = (const float*)d_in[7];  // [1024,1]
    const float* bd     = (const float*)d_in[8];  // [1]
    float* out = (float*)d_out;                   // [64, 16*128, 1]

    char* ws = (char*)d_ws;
    size_t off = 0;
    auto carve = [&](size_t bytes) -> void* {
        void* p = ws + off;
        off += (bytes + 255) & ~(size_t)255;
        return p;
    };
    unsigned short* W1hi = (unsigned short*)carve((size_t)FOURU * UU * 2);
    unsigned short* W1lo = (unsigned short*)carve((size_t)FOURU * UU * 2);
    unsigned short* W2hi = (unsigned short*)carve((size_t)FOURU * 2048 * 2);
    unsigned short* W2lo = (unsigned short*)carve((size_t)FOURU * 2048 * 2);
    unsigned short* X1hi = (unsigned short*)carve((size_t)TTT * BU * 2);
    unsigned short* X1lo = (unsigned short*)carve((size_t)TTT * BU * 2);
    unsigned short* X2hi = (unsigned short*)carve((size_t)TTT * BU * 2);
    unsigned short* X2lo = (unsigned short*)carve((size_t)TTT * BU * 2);
    unsigned int* bar = (unsigned int*)carve(256);

    bar_init<<<dim3(1), dim3(64), 0, stream>>>(bar);
    repack_w1<<<dim3((FOURU * UU) / 256), dim3(256), 0, stream>>>(r1, W1hi, W1lo);
    repack_w2<<<dim3((FOURU * 2048) / 256), dim3(256), 0, stream>>>(k2, r2, W2hi, W2lo);

    feedback_persistent<<<dim3(NBLK), dim3(512), 0, stream>>>(
        W1hi, W1lo, W2hi, W2lo, X1hi, X1lo, X2hi, X2lo,
        inputs, k1, b1, b2, wd, bd, out, bar);
}

// Round 7
// 90752.075 us; speedup vs baseline: 1.8590x; 1.3239x over previous
//
#include <hip/hip_runtime.h>
#include <cstdint>
#include <cstddef>

#define UU 1024
#define FOURU 4096
#define BATCH 64
#define TTT 128
#define SSS 16
#define BU 65536  // BATCH*UU elems per time plane
#define NBLK 256
#define NW 8      // waves per block

typedef __attribute__((ext_vector_type(8))) short short8;
typedef __attribute__((ext_vector_type(4))) float f32x4;

__device__ __forceinline__ unsigned short f2bf(float f) {
    union { float f; uint32_t u; } v; v.f = f;
    uint32_t u = v.u;
    uint32_t r = (u + 0x7fffu + ((u >> 16) & 1u)) >> 16;
    return (unsigned short)r;
}
__device__ __forceinline__ float bf2f(unsigned short h) {
    union { uint32_t u; float f; } v; v.u = ((uint32_t)h) << 16;
    return v.f;
}

// ---------------------------------------------------------------------------
// Flag-array grid barrier (no RMW, no central counter).
// flags = 256 cachelines (16 dwords apart). Block blk release-stores
// flags[blk*16] = ns (wbl2 publishes its h stores). Threads 0..255 poll
// flags[i*16] >= ns with RELAXED agent loads (read-through, no inv).
// Then ONE ACQUIRE load per block (single buffer_inv) before consuming.
// ns is a monotonically increasing step id -> no reset, no sense reversal.
// ---------------------------------------------------------------------------
__device__ __forceinline__ void grid_barrier(unsigned int* flags, unsigned int ns) {
    __syncthreads();   // all waves drain vmcnt -> block's h stores are in L2
    const int tid = threadIdx.x;
    if (tid == 0) {
        __hip_atomic_store(flags + (size_t)blockIdx.x * 16, ns,
                           __ATOMIC_RELEASE, __HIP_MEMORY_SCOPE_AGENT);
    }
    if (tid < NBLK) {
        while (__hip_atomic_load(flags + (size_t)tid * 16,
                                 __ATOMIC_RELAXED, __HIP_MEMORY_SCOPE_AGENT) < ns) {
            __builtin_amdgcn_s_sleep(1);
        }
    }
    __syncthreads();   // everyone observed all flags
    if (tid == 0) {
        (void)__hip_atomic_load(flags + (size_t)blockIdx.x * 16,
                                __ATOMIC_ACQUIRE, __HIP_MEMORY_SCOPE_AGENT);
    }
    __syncthreads();   // inv done before anyone reads h
}

__global__ void bar_init(unsigned int* flags) {
    flags[blockIdx.x * 256 + threadIdx.x] = 0u;  // 4096 dwords = 16 KB
}

// ---------------------------------------------------------------------------
// Repack weights: W[k][origcol] f32 -> packed [pc][K] bf16 hi/lo;
// pc = blk*16 + g*4 + j <-> origcol = g*1024 + blk*4 + j.
// ---------------------------------------------------------------------------
__global__ void repack_w1(const float* __restrict__ r1,
                          unsigned short* __restrict__ whi,
                          unsigned short* __restrict__ wlo) {
    int idx = blockIdx.x * 256 + threadIdx.x;
    int pc = idx >> 10, k = idx & 1023;
    int b = pc >> 4, g = (pc >> 2) & 3, j = pc & 3;
    int oc = g * UU + b * 4 + j;
    float v = r1[(size_t)k * FOURU + oc];
    unsigned short hi = f2bf(v);
    whi[idx] = hi;
    wlo[idx] = f2bf(v - bf2f(hi));
}

__global__ void repack_w2(const float* __restrict__ k2, const float* __restrict__ r2,
                          unsigned short* __restrict__ whi,
                          unsigned short* __restrict__ wlo) {
    int idx = blockIdx.x * 256 + threadIdx.x;
    int pc = idx >> 11, k = idx & 2047;
    int b = pc >> 4, g = (pc >> 2) & 3, j = pc & 3;
    int oc = g * UU + b * 4 + j;
    float v = (k < UU) ? k2[(size_t)k * FOURU + oc]
                       : r2[(size_t)(k - UU) * FOURU + oc];
    unsigned short hi = f2bf(v);
    whi[idx] = hi;
    wlo[idx] = f2bf(v - bf2f(hi));
}

// ---------------------------------------------------------------------------
// Persistent kernel: 256 blocks x 512 threads (8 waves), 1 block/CU.
// Block blk owns packed cols blk*16..+15 for BOTH layers. 8 waves split K.
// Weights pinned in VGPRs (opaque asm). h via global bf16 hi/lo planes;
// c in per-thread registers. One flag-array grid barrier per cell step.
// ---------------------------------------------------------------------------
__global__ __launch_bounds__(512, 1) void feedback_persistent(
    const unsigned short* __restrict__ W1hi, const unsigned short* __restrict__ W1lo,
    const unsigned short* __restrict__ W2hi, const unsigned short* __restrict__ W2lo,
    unsigned short* __restrict__ X1hi, unsigned short* __restrict__ X1lo,
    unsigned short* __restrict__ X2hi, unsigned short* __restrict__ X2lo,
    const float* __restrict__ inputs, const float* __restrict__ k1,
    const float* __restrict__ b1, const float* __restrict__ b2,
    const float* __restrict__ wd, const float* __restrict__ bd,
    float* __restrict__ out, unsigned int* flags) {
    __shared__ float zp[NW][64][17];

    const int tid = threadIdx.x;
    const int lane = tid & 63;
    const int w = tid >> 6;          // 0..7
    const int blk = blockIdx.x;
    const int kg8 = (lane >> 4) * 8;
    const int colpc = blk * 16 + (lane & 15);

    // ---- weights -> VGPRs (once); opaque-pin so they cannot be remat'd ----
    short8 w1h[4], w1l[4], w2h[8], w2l[8];
    {
        const size_t base1 = (size_t)colpc * 1024 + (size_t)w * 128 + kg8;
#pragma unroll
        for (int i = 0; i < 4; ++i) {
            w1h[i] = *(const short8*)(W1hi + base1 + i * 32);
            w1l[i] = *(const short8*)(W1lo + base1 + i * 32);
            asm volatile("" : "+v"(w1h[i]), "+v"(w1l[i]));
        }
        const size_t base2 = (size_t)colpc * 2048 + (size_t)w * 256 + kg8;
#pragma unroll
        for (int i = 0; i < 8; ++i) {
            w2h[i] = *(const short8*)(W2hi + base2 + i * 32);
            w2l[i] = *(const short8*)(W2lo + base2 + i * 32);
            asm volatile("" : "+v"(w2h[i]), "+v"(w2l[i]));
        }
    }

    // ---- epilogue mapping: first 256 threads, (row, unit) ----
    const int erow = (tid & 255) >> 2;   // 0..63
    const int ej = tid & 3;              // 0..3
    const int eu = blk * 4 + ej;
    float b1v[4], b2v[4], k1v[4];
#pragma unroll
    for (int g = 0; g < 4; ++g) {
        const int oc = g * UU + blk * 4 + ej;
        b1v[g] = b1[oc];
        b2v[g] = b2[oc];
        k1v[g] = k1[oc];
    }
    float c1 = 0.f, c2 = 0.f;

    const int gw = blk * NW + w;  // 0..2047 global wave id
    unsigned int ns = 1;          // monotonic barrier step id

    for (int s = 0; s < SSS; ++s) {
        // ================= LSTM1 scan (K=1024, 128/wave) ===================
        for (int t = 0; t < TTT; ++t) {
            f32x4 acc[4] = {};
            if (!(s == 0 && t == 0)) {
                const unsigned short *Ah, *Al;
                if (t == 0) { Ah = X2hi + 127 * BU; Al = X2lo + 127 * BU; }
                else        { Ah = X1hi + (size_t)(t - 1) * BU; Al = X1lo + (size_t)(t - 1) * BU; }
                const int koff = w * 128;
#pragma unroll
                for (int i = 0; i < 4; ++i) {
                    const int kk = i * 32;
#pragma unroll
                    for (int m = 0; m < 4; ++m) {
                        const int row = m * 16 + (lane & 15);
                        const size_t aoff = (size_t)row * UU + koff + kk + kg8;
                        short8 ah = *(const short8*)(Ah + aoff);
                        short8 al = *(const short8*)(Al + aoff);
                        acc[m] = __builtin_amdgcn_mfma_f32_16x16x32_bf16(ah, w1h[i], acc[m], 0, 0, 0);
                        acc[m] = __builtin_amdgcn_mfma_f32_16x16x32_bf16(al, w1h[i], acc[m], 0, 0, 0);
                        acc[m] = __builtin_amdgcn_mfma_f32_16x16x32_bf16(ah, w1l[i], acc[m], 0, 0, 0);
                    }
                }
            }
#pragma unroll
            for (int m = 0; m < 4; ++m) {
                const int rbase = m * 16 + (lane >> 4) * 4;
#pragma unroll
                for (int r = 0; r < 4; ++r)
                    zp[w][rbase + r][lane & 15] = acc[m][r];
            }
            __syncthreads();
            if (tid < 256) {
                float xv = (s == 0) ? inputs[(size_t)erow * TTT + t]
                                    : out[(size_t)erow * (SSS * TTT) + (s - 1) * TTT + t];
                float z[4];
#pragma unroll
                for (int g = 0; g < 4; ++g) {
                    float sum = 0.f;
#pragma unroll
                    for (int ww = 0; ww < NW; ++ww) sum += zp[ww][erow][g * 4 + ej];
                    z[g] = sum + b1v[g] + xv * k1v[g];
                }
                float cold = (t == 0) ? c2 : c1;  // c2: 0 at s==0; lstm2 final c of s-1 else
                float ig = 1.f / (1.f + expf(-z[0]));
                float fg = 1.f / (1.f + expf(-z[1]));
                float gg = tanhf(z[2]);
                float og = 1.f / (1.f + expf(-z[3]));
                float cn = fg * cold + ig * gg;
                float hn = og * tanhf(cn);
                c1 = cn;
                unsigned short hh = f2bf(hn);
                const size_t hoff = (size_t)t * BU + (size_t)erow * UU + eu;
                X1hi[hoff] = hh;
                X1lo[hoff] = f2bf(hn - bf2f(hh));
            }
            grid_barrier(flags, ns++);
        }
        // ================= LSTM2 scan (K=2048, 256/wave) ===================
        for (int t = 0; t < TTT; ++t) {
            f32x4 acc[4] = {};
            const bool skiph = (s == 0 && t == 0);  // warmup: h2_0 = 0
            {
                const unsigned short *Ah, *Al;
                int koff;
                if (w < 4) {  // x half, k in [0,1024)
                    Ah = X1hi + (size_t)t * BU;
                    Al = X1lo + (size_t)t * BU;
                    koff = w * 256;
                } else {      // h half, k in [1024,2048)
                    if (t == 0) { Ah = X1hi + 127 * BU; Al = X1lo + 127 * BU; }  // h2_init = h1_final
                    else        { Ah = X2hi + (size_t)(t - 1) * BU; Al = X2lo + (size_t)(t - 1) * BU; }
                    koff = (w - 4) * 256;
                }
                if (!(skiph && w >= 4)) {
#pragma unroll
                    for (int i = 0; i < 8; ++i) {
                        const int kk = i * 32;
#pragma unroll
                        for (int m = 0; m < 4; ++m) {
                            const int row = m * 16 + (lane & 15);
                            const size_t aoff = (size_t)row * UU + koff + kk + kg8;
                            short8 ah = *(const short8*)(Ah + aoff);
                            short8 al = *(const short8*)(Al + aoff);
                            acc[m] = __builtin_amdgcn_mfma_f32_16x16x32_bf16(ah, w2h[i], acc[m], 0, 0, 0);
                            acc[m] = __builtin_amdgcn_mfma_f32_16x16x32_bf16(al, w2h[i], acc[m], 0, 0, 0);
                            acc[m] = __builtin_amdgcn_mfma_f32_16x16x32_bf16(ah, w2l[i], acc[m], 0, 0, 0);
                        }
                    }
                }
            }
#pragma unroll
            for (int m = 0; m < 4; ++m) {
                const int rbase = m * 16 + (lane >> 4) * 4;
#pragma unroll
                for (int r = 0; r < 4; ++r)
                    zp[w][rbase + r][lane & 15] = acc[m][r];
            }
            __syncthreads();
            if (tid < 256) {
                float z[4];
#pragma unroll
                for (int g = 0; g < 4; ++g) {
                    float sum = 0.f;
#pragma unroll
                    for (int ww = 0; ww < NW; ++ww) sum += zp[ww][erow][g * 4 + ej];
                    z[g] = sum + b2v[g];
                }
                float cold = (t == 0) ? ((s == 0) ? 0.f : c1) : c2;
                float ig = 1.f / (1.f + expf(-z[0]));
                float fg = 1.f / (1.f + expf(-z[1]));
                float gg = tanhf(z[2]);
                float og = 1.f / (1.f + expf(-z[3]));
                float cn = fg * cold + ig * gg;
                float hn = og * tanhf(cn);
                c2 = cn;
                unsigned short hh = f2bf(hn);
                const size_t hoff = (size_t)t * BU + (size_t)erow * UU + eu;
                X2hi[hoff] = hh;
                X2lo[hoff] = f2bf(hn - bf2f(hh));
            }
            grid_barrier(flags, ns++);
        }
        // ================= dense head over full sequence ====================
        // 2048 waves x 4 dots = 8192 (t,b) dot products of length 1024
#pragma unroll
        for (int i = 0; i < 4; ++i) {
            const int d = gw + 2048 * i;
            const int t = d >> 6, b = d & 63;
            const unsigned short* ph = X2hi + (size_t)t * BU + (size_t)b * UU;
            const unsigned short* pl = X2lo + (size_t)t * BU + (size_t)b * UU;
            float ssum = 0.f;
#pragma unroll 4
            for (int ii = lane; ii < UU; ii += 64)
                ssum += (bf2f(ph[ii]) + bf2f(pl[ii])) * wd[ii];
#pragma unroll
            for (int off = 32; off; off >>= 1) ssum += __shfl_down(ssum, off, 64);
            if (lane == 0) out[(size_t)b * (SSS * TTT) + s * TTT + t] = ssum + bd[0];
        }
        grid_barrier(flags, ns++);
    }
}

// ---------------------------------------------------------------------------
extern "C" void kernel_launch(void* const* d_in, const int* in_sizes, int n_in,
                              void* d_out, int out_size, void* d_ws, size_t ws_size,
                              hipStream_t stream) {
    const float* inputs = (const float*)d_in[0];  // [64,128,1]
    const float* k1     = (const float*)d_in[1];  // [1,4096]
    const float* r1     = (const float*)d_in[2];  // [1024,4096]
    const float* b1     = (const float*)d_in[3];  // [4096]
    const float* k2     = (const float*)d_in[4];  // [1024,4096]
    const float* r2     = (const float*)d_in[5];  // [1024,4096]
    const float* b2     = (const float*)d_in[6];  // [4096]
    const float* wd     = (const float*)d_in[7];  // [1024,1]
    const float* bd     = (const float*)d_in[8];  // [1]
    float* out = (float*)d_out;                   // [64, 16*128, 1]

    char* ws = (char*)d_ws;
    size_t off = 0;
    auto carve = [&](size_t bytes) -> void* {
        void* p = ws + off;
        off += (bytes + 255) & ~(size_t)255;
        return p;
    };
    unsigned short* W1hi = (unsigned short*)carve((size_t)FOURU * UU * 2);
    unsigned short* W1lo = (unsigned short*)carve((size_t)FOURU * UU * 2);
    unsigned short* W2hi = (unsigned short*)carve((size_t)FOURU * 2048 * 2);
    unsigned short* W2lo = (unsigned short*)carve((size_t)FOURU * 2048 * 2);
    unsigned short* X1hi = (unsigned short*)carve((size_t)TTT * BU * 2);
    unsigned short* X1lo = (unsigned short*)carve((size_t)TTT * BU * 2);
    unsigned short* X2hi = (unsigned short*)carve((size_t)TTT * BU * 2);
    unsigned short* X2lo = (unsigned short*)carve((size_t)TTT * BU * 2);
    unsigned int* flags = (unsigned int*)carve(NBLK * 64);

    bar_init<<<dim3(16), dim3(256), 0, stream>>>(flags);
    repack_w1<<<dim3((FOURU * UU) / 256), dim3(256), 0, stream>>>(r1, W1hi, W1lo);
    repack_w2<<<dim3((FOURU * 2048) / 256), dim3(256), 0, stream>>>(k2, r2, W2hi, W2lo);

    feedback_persistent<<<dim3(NBLK), dim3(512), 0, stream>>>(
        W1hi, W1lo, W2hi, W2lo, X1hi, X1lo, X2hi, X2lo,
        inputs, k1, b1, b2, wd, bd, out, flags);
}